// Round 8
// baseline (273.551 us; speedup 1.0000x reference)
//
#include <hip/hip_runtime.h>
#include <math.h>

// out[b,c,n] = softmax_n(max_c x[b,c,n]) * x[b,c,n]   (x: [256,64,2048] fp32)
//
// R9b: fix of R9's compile error — __builtin_nontemporal_store needs a
// NATIVE clang vector type, not HIP's float4 class. Logic unchanged:
// true read-once. Each half-row thread holds all 32 channels in registers
// (128 data VGPRs; 16-wave block = 4 waves/SIMD so 512 VGPR/wave is
// launchable), pinned with an opaque asm barrier so the compiler can't
// rematerialize the loads in phase 2. Phase 2 = pure nontemporal write
// stream (~6.7 TB/s). Expected kernel ~43us read + ~5us softmax + ~19us
// write ~= 67-75us vs 91us (R0 double-read) / 100us (R8 spilled).

#define B_DIM 256
#define C_DIM 64
#define N_DIM 2048
#define COLS4 (N_DIM / 4)          // 512 float4 columns per row
#define ROW4  (C_DIM * COLS4)      // 32768 float4 per batch row

#define CH_HALF 32                 // channels per half-row (all in regs)

typedef float v4f __attribute__((ext_vector_type(4)));

#define PIN4(v) asm volatile("" : "+v"(v.x), "+v"(v.y), "+v"(v.z), "+v"(v.w))

__global__ __launch_bounds__(1024, 4)
void ssa_gate_fused(const float* __restrict__ x, float* __restrict__ out) {
    const int b    = blockIdx.x;
    const int t    = threadIdx.x;
    const int col  = t & (COLS4 - 1);   // 0..511
    const int grp  = t >> 9;            // 0 -> ch 0..31, 1 -> ch 32..63
    const int lane = t & 63;
    const int wid  = t >> 6;            // 0..15
    const int c0   = grp * CH_HALF;

    const float4* __restrict__ xb = (const float4*)x + (size_t)b * ROW4;
    v4f* __restrict__ ob = (v4f*)out + (size_t)b * ROW4;

    __shared__ float4 xmbuf[COLS4];     // 8 KB: xm partial, then gate
    __shared__ float  sredM[16];
    __shared__ float  sredS[16];

    // ---- Phase 1: read this half's 32 channels ONCE into registers ----
    float4 r[CH_HALF];
    float4 m = make_float4(-INFINITY, -INFINITY, -INFINITY, -INFINITY);
    #pragma unroll
    for (int c = 0; c < CH_HALF; ++c) {
        r[c] = xb[(size_t)(c0 + c) * COLS4 + col];
        m.x = fmaxf(m.x, r[c].x); m.y = fmaxf(m.y, r[c].y);
        m.z = fmaxf(m.z, r[c].z); m.w = fmaxf(m.w, r[c].w);
    }
    // Pin the row in registers: opaque to the optimizer, so the loads cannot
    // be sunk/rematerialized into phase 2 and the values must stay resident.
    #pragma unroll
    for (int c = 0; c < CH_HALF; ++c) { PIN4(r[c]); }

    // ---- Combine halves -> xm per column, then block softmax ----
    if (grp == 1) xmbuf[col] = m;
    __syncthreads();

    float4 e;
    float tm = -INFINITY;
    if (grp == 0) {
        float4 o = xmbuf[col];
        e.x = fmaxf(m.x, o.x); e.y = fmaxf(m.y, o.y);
        e.z = fmaxf(m.z, o.z); e.w = fmaxf(m.w, o.w);
        tm = fmaxf(fmaxf(e.x, e.y), fmaxf(e.z, e.w));
    }
    #pragma unroll
    for (int off = 32; off > 0; off >>= 1)
        tm = fmaxf(tm, __shfl_down(tm, off, 64));
    if (lane == 0) sredM[wid] = tm;     // grp1 waves write -inf: harmless
    __syncthreads();
    float M = sredM[0];
    #pragma unroll
    for (int i = 1; i < 16; ++i) M = fmaxf(M, sredM[i]);

    float ts = 0.0f;
    if (grp == 0) {
        e.x = __expf(e.x - M); e.y = __expf(e.y - M);
        e.z = __expf(e.z - M); e.w = __expf(e.w - M);
        ts = (e.x + e.y) + (e.z + e.w);
    }
    #pragma unroll
    for (int off = 32; off > 0; off >>= 1)
        ts += __shfl_down(ts, off, 64);
    if (lane == 0) sredS[wid] = ts;     // grp1 waves contribute 0
    __syncthreads();
    float S = 0.0f;
    #pragma unroll
    for (int i = 0; i < 16; ++i) S += sredS[i];

    if (grp == 0) {
        const float inv = 1.0f / S;
        float4 g;
        g.x = e.x * inv; g.y = e.y * inv; g.z = e.z * inv; g.w = e.w * inv;
        xmbuf[col] = g;                 // overwrite partial with gate
    }
    __syncthreads();
    const float4 g = xmbuf[col];

    // ---- Phase 2: pure write stream, no global reads ----
    #pragma unroll
    for (int c = 0; c < CH_HALF; ++c) {
        v4f w;
        w.x = r[c].x * g.x; w.y = r[c].y * g.y;
        w.z = r[c].z * g.z; w.w = r[c].w * g.w;
        __builtin_nontemporal_store(w, &ob[(size_t)(c0 + c) * COLS4 + col]);
    }
}

extern "C" void kernel_launch(void* const* d_in, const int* in_sizes, int n_in,
                              void* d_out, int out_size, void* d_ws, size_t ws_size,
                              hipStream_t stream) {
    const float* x = (const float*)d_in[0];
    float* out = (float*)d_out;
    ssa_gate_fused<<<B_DIM, 1024, 0, stream>>>(x, out);
}